// Round 5
// baseline (39543.103 us; speedup 1.0000x reference)
//
#include <hip/hip_runtime.h>
#include <hip/hip_bf16.h>

// ---------------------------------------------------------------------------
// Seq2SeqAttention R5: ONE persistent kernel (256 blocks x 512 threads,
// 1 block/CU co-resident) runs encoder(512 steps) + P-GEMM + decoder(30
// steps). Grid barriers: monotonic counter + agent-scope fences. Theory:
// R2/R4 were dominated by ~40us/dispatch boundary cost (733 launches);
// persistent kernel removes it and keeps weights L2/L3-hot across steps.
// c-state lives in registers (owner thread fixed across steps).
// Numerics identical to R4 (split-bf16 MFMA, fp16 P dual-region).
// ---------------------------------------------------------------------------

static constexpr int T_ = 512, B_ = 128, I_ = 256, H_ = 1024, O_ = 256;
static constexpr int NB_ = 256, BS_ = 512;
static constexpr int BH_ = B_ * H_;

typedef unsigned short ushort;
typedef __attribute__((ext_vector_type(8))) short bf16x8;
typedef __attribute__((ext_vector_type(4))) float f32x4;
typedef __attribute__((ext_vector_type(8))) _Float16 half8;

// ---- ws layout (bytes). Layout B total = 239.6MB (< proven 271.8MB floor).
static constexpr size_t SZ_4HH = (size_t)4*H_*H_*2, SZ_4HI = (size_t)4*H_*I_*2,
    SZ_HH = (size_t)H_*H_*2, SZ_OH = (size_t)O_*H_*2, SZ_BH2 = (size_t)BH_*2,
    SZ_BH4 = (size_t)BH_*4, SZ_TBH2 = (size_t)T_*BH_*2, SZ_BT4 = (size_t)B_*T_*4,
    SZ_PH = (size_t)(T_/2)*BH_*2;
static constexpr size_t O_WHHE_H = 256,
    O_WHHE_L = O_WHHE_H + SZ_4HH, O_WIHE_H = O_WHHE_L + SZ_4HH,
    O_WIHE_L = O_WIHE_H + SZ_4HI, O_WH_H = O_WIHE_L + SZ_4HI,
    O_WH_L = O_WH_H + SZ_HH, O_WC_H = O_WH_L + SZ_HH, O_WC_L = O_WC_H + SZ_HH,
    O_WDEC_H = O_WC_L + SZ_HH, O_WDEC_L = O_WDEC_H + SZ_HH,
    O_WOUT_H = O_WDEC_L + SZ_HH, O_WOUT_L = O_WOUT_H + SZ_OH,
    O_CTX = O_WOUT_L + SZ_OH,
    O_ELO0 = O_CTX + SZ_TBH2, O_ELO1 = O_ELO0 + SZ_BH2,
    O_DHH0 = O_ELO1 + SZ_BH2, O_DHH1 = O_DHH0 + SZ_BH2,
    O_DHL0 = O_DHH1 + SZ_BH2, O_DHL1 = O_DHL0 + SZ_BH2,
    O_CHI = O_DHL1 + SZ_BH2, O_CLO = O_CHI + SZ_BH2,
    O_D1H = O_CLO + SZ_BH2, O_D1L = O_D1H + SZ_BH2,
    O_QBUF = O_D1L + SZ_BH2, O_SCORES = O_QBUF + SZ_BH4,
    O_P1 = O_SCORES + SZ_BT4, O_P0A = O_P1 + SZ_PH,
    WS_NEED_A = O_P0A + SZ_PH;

__device__ __forceinline__ float bf2f(ushort u) {
    union { unsigned i; float f; } cv; cv.i = ((unsigned)u) << 16; return cv.f;
}
__device__ __forceinline__ ushort f2bf(float f) {   // RNE
    union { float f; unsigned u; } c; c.f = f;
    unsigned r = c.u + 0x7FFFu + ((c.u >> 16) & 1u);
    return (ushort)(r >> 16);
}
__device__ __forceinline__ float fast_sigmoid(float x) { return 1.f / (1.f + __expf(-x)); }
__device__ __forceinline__ float fast_tanh(float x) {
    float ax = fabsf(x);
    float e = __expf(-2.f * ax);
    float t = (1.f - e) / (1.f + e);
    return copysignf(t, x);
}
__device__ __forceinline__ f32x4 mfma16(bf16x8 a, bf16x8 b, f32x4 c) {
    return __builtin_amdgcn_mfma_f32_16x16x32_bf16(a, b, c, 0, 0, 0);
}
__device__ __forceinline__ bf16x8 ld8(const ushort* p) { return *(const bf16x8*)(const void*)p; }
__device__ __forceinline__ void split8(const float* p, bf16x8& hi, bf16x8& lo) {
    #pragma unroll
    for (int j = 0; j < 8; j++) {
        const float f = p[j];
        const ushort h = f2bf(f);
        hi[j] = (short)h;
        lo[j] = (short)f2bf(f - bf2f(h));
    }
}

// ---- grid barrier: monotonic counter, agent-scope fences -------------------
__device__ __forceinline__ void gbar(unsigned* cnt, unsigned target) {
    __syncthreads();
    if (threadIdx.x == 0) {
        __builtin_amdgcn_fence(__ATOMIC_RELEASE, "agent");   // flush my writes
        __hip_atomic_fetch_add(cnt, 1u, __ATOMIC_RELAXED, __HIP_MEMORY_SCOPE_AGENT);
        while (__hip_atomic_load(cnt, __ATOMIC_RELAXED, __HIP_MEMORY_SCOPE_AGENT) < target)
            __builtin_amdgcn_s_sleep(2);
        __builtin_amdgcn_fence(__ATOMIC_ACQUIRE, "agent");   // drop stale lines
    }
    __syncthreads();
}

// ---- one LSTM step: block g owns 4 h-cols x 4 gates x all 128 rows ---------
template<bool WPRE, bool XPRE, int KX>
__device__ __forceinline__ void lstm_phase(
    int g, int tid,
    const ushort* __restrict__ hhi, const ushort* __restrict__ hlo, bool with_h,
    const void* __restrict__ xa, const ushort* __restrict__ xlo,
    const void* __restrict__ WhhA, const ushort* __restrict__ WhhL,
    const void* __restrict__ WihA, const ushort* __restrict__ WihL,
    const float* __restrict__ bih, const float* __restrict__ bhh,
    float& c_reg, ushort* __restrict__ ohi, ushort* __restrict__ olo,
    float (*Gt)[130])
{
    const int wave = tid >> 6, lane = tid & 63;
    const int quad = lane >> 4, l15 = lane & 15;
    const int h0 = g << 2;
    const size_t arow = (size_t)(wave * 16 + l15);
    const int wr = ((l15 >> 2) * H_) + h0 + (l15 & 3);   // gate*H + h row of W

    f32x4 a0 = {0.f,0.f,0.f,0.f}, a1 = a0, a2 = a0;
    if (with_h) {
        const size_t aoff = arow * H_;
        const size_t woff = (size_t)wr * H_;
        #pragma unroll 4
        for (int kc = 0; kc < H_; kc += 32) {
            const int ko = kc + quad * 8;
            bf16x8 bh, bl;
            if constexpr (WPRE) {
                bh = ld8((const ushort*)WhhA + woff + ko);
                bl = ld8(WhhL + woff + ko);
            } else {
                split8((const float*)WhhA + woff + ko, bh, bl);
            }
            const bf16x8 ah = ld8(hhi + aoff + ko);
            const bf16x8 al = ld8(hlo + aoff + ko);
            a0 = mfma16(ah, bh, a0); a1 = mfma16(ah, bl, a1); a2 = mfma16(al, bh, a2);
        }
    }
    {
        const size_t woff = (size_t)wr * KX;
        const size_t xoff = arow * KX;
        #pragma unroll 2
        for (int kc = 0; kc < KX; kc += 32) {
            const int ko = kc + quad * 8;
            bf16x8 bh, bl;
            if constexpr (WPRE) {
                bh = ld8((const ushort*)WihA + woff + ko);
                bl = ld8(WihL + woff + ko);
            } else {
                split8((const float*)WihA + woff + ko, bh, bl);
            }
            bf16x8 ah, al;
            if constexpr (XPRE) {
                ah = ld8((const ushort*)xa + xoff + ko);
                al = ld8(xlo + xoff + ko);
            } else {
                split8((const float*)xa + xoff + ko, ah, al);
            }
            a0 = mfma16(ah, bh, a0); a1 = mfma16(ah, bl, a1); a2 = mfma16(al, bh, a2);
        }
    }
    // gate exchange: Gt[col(gate*4+hl)][row]; D row = quad*4+r, col = l15
    #pragma unroll
    for (int r = 0; r < 4; r++)
        Gt[l15][wave * 16 + quad * 4 + r] = a0[r] + a1[r] + a2[r];
    __syncthreads();
    const int b = tid >> 2, hl = tid & 3;
    const int hidx = h0 + hl;
    const float gi = Gt[hl][b]        + bih[hidx]          + bhh[hidx];
    const float gf = Gt[4 + hl][b]    + bih[H_ + hidx]     + bhh[H_ + hidx];
    const float gg = Gt[8 + hl][b]    + bih[2 * H_ + hidx] + bhh[2 * H_ + hidx];
    const float go = Gt[12 + hl][b]   + bih[3 * H_ + hidx] + bhh[3 * H_ + hidx];
    const float ig = fast_sigmoid(gi), fg = fast_sigmoid(gf);
    const float gt = fast_tanh(gg),    og = fast_sigmoid(go);
    const float cnew = fg * c_reg + ig * gt;
    const float hnew = og * fast_tanh(cnew);
    c_reg = cnew;
    const ushort hh2 = f2bf(hnew);
    ohi[b * H_ + hidx] = hh2;
    olo[b * H_ + hidx] = f2bf(hnew - bf2f(hh2));
}

// ---- one 16x16 output tile of A(split) @ W(split)^T, K templated -----------
template<int K>
__device__ __forceinline__ f32x4 mm16_split(
    const ushort* __restrict__ Ahi, const ushort* __restrict__ Alo, size_t aoff,
    const ushort* __restrict__ Whi, const ushort* __restrict__ Wlo, size_t woff,
    int quad)
{
    f32x4 a0 = {0.f,0.f,0.f,0.f}, a1 = a0, a2 = a0;
    #pragma unroll 2
    for (int kc = 0; kc < K; kc += 32) {
        const int ko = kc + quad * 8;
        const bf16x8 ah = ld8(Ahi + aoff + ko);
        const bf16x8 al = ld8(Alo + aoff + ko);
        const bf16x8 bh = ld8(Whi + woff + ko);
        const bf16x8 bl = ld8(Wlo + woff + ko);
        a0 = mfma16(ah, bh, a0); a1 = mfma16(ah, bl, a1); a2 = mfma16(al, bh, a2);
    }
    return a0 + a1 + a2;
}

// ---------------------------------------------------------------------------
__global__ __launch_bounds__(BS_, 2) void mega_kernel(
    const float* __restrict__ input_seq,
    const float* __restrict__ W_ih_enc, const float* __restrict__ W_hh_enc,
    const float* __restrict__ b_ih_enc, const float* __restrict__ b_hh_enc,
    const float* __restrict__ W_attn, const float* __restrict__ b_attn,
    const float* __restrict__ vvec,
    const float* __restrict__ W_ih_dec, const float* __restrict__ W_hh_dec,
    const float* __restrict__ b_ih_dec, const float* __restrict__ b_hh_dec,
    const float* __restrict__ W_dec, const float* __restrict__ b_dec,
    const float* __restrict__ W_out, const float* __restrict__ b_out,
    float* __restrict__ out, char* __restrict__ ws, int LEN, int layoutA)
{
    __shared__ float Gt[16][130];
    const int g = blockIdx.x, tid = threadIdx.x;
    const int wave = tid >> 6, lane = tid & 63;
    const int quad = lane >> 4, l15 = lane & 15;
    const int wg = g * 8 + wave;                 // global wave id, 0..2047

    unsigned* cnt = (unsigned*)ws;
    ushort* WhhE_h = (ushort*)(ws + O_WHHE_H); ushort* WhhE_l = (ushort*)(ws + O_WHHE_L);
    ushort* WihE_h = (ushort*)(ws + O_WIHE_H); ushort* WihE_l = (ushort*)(ws + O_WIHE_L);
    ushort* Wh_h = (ushort*)(ws + O_WH_H);     ushort* Wh_l = (ushort*)(ws + O_WH_L);
    ushort* Wc_h = (ushort*)(ws + O_WC_H);     ushort* Wc_l = (ushort*)(ws + O_WC_L);
    ushort* Wdec_h = (ushort*)(ws + O_WDEC_H); ushort* Wdec_l = (ushort*)(ws + O_WDEC_L);
    ushort* Wout_h = (ushort*)(ws + O_WOUT_H); ushort* Wout_l = (ushort*)(ws + O_WOUT_L);
    ushort* ctx_seq = (ushort*)(ws + O_CTX);
    ushort* elo0 = (ushort*)(ws + O_ELO0); ushort* elo1 = (ushort*)(ws + O_ELO1);
    ushort* dhh0 = (ushort*)(ws + O_DHH0); ushort* dhh1 = (ushort*)(ws + O_DHH1);
    ushort* dhl0 = (ushort*)(ws + O_DHL0); ushort* dhl1 = (ushort*)(ws + O_DHL1);
    ushort* chi = (ushort*)(ws + O_CHI);   ushort* clo = (ushort*)(ws + O_CLO);
    ushort* d1h = (ushort*)(ws + O_D1H);   ushort* d1l = (ushort*)(ws + O_D1L);
    float* qbuf = (float*)(ws + O_QBUF);
    float* scores = (float*)(ws + O_SCORES);
    _Float16* P1 = (_Float16*)(ws + O_P1);
    _Float16* P0 = layoutA ? (_Float16*)(ws + O_P0A) : (_Float16*)input_seq;
    const size_t HALF_IDX = (size_t)(T_ / 2) * BH_;

    unsigned bars = 0;
    auto BAR = [&]() { bars++; gbar(cnt, bars * NB_); };

    // ================= phase 0: split all pre-split weights ================
    {
        auto split_range = [&](const float* src, int srcld, int coloff,
                               ushort* hi, ushort* lo, int R, int logK) {
            const int K = 1 << logK;
            const int total = R << logK;
            for (int i = g * BS_ + tid; i < total; i += NB_ * BS_) {
                const int r = i >> logK, k = i & (K - 1);
                const float f = src[(size_t)r * srcld + coloff + k];
                const ushort h = f2bf(f);
                hi[i] = h; lo[i] = f2bf(f - bf2f(h));
            }
        };
        split_range(W_hh_enc, H_,     0,  WhhE_h, WhhE_l, 4 * H_, 10);
        split_range(W_ih_enc, I_,     0,  WihE_h, WihE_l, 4 * H_, 8);
        split_range(W_attn,   2 * H_, 0,  Wh_h,   Wh_l,   H_,     10);
        split_range(W_attn,   2 * H_, H_, Wc_h,   Wc_l,   H_,     10);
        split_range(W_dec,    H_,     0,  Wdec_h, Wdec_l, H_,     10);
        split_range(W_out,    H_,     0,  Wout_h, Wout_l, O_,     10);
    }
    BAR();

    // ================= encoder: 512 steps ==================================
    float c_enc = 0.f;
    {
        ushort* elo[2] = {elo0, elo1};
        for (int t = 0; t < T_; t++) {
            const ushort* hhi = (t == 0) ? ctx_seq : ctx_seq + (size_t)(t - 1) * BH_;
            const ushort* hlo = elo[t & 1];
            lstm_phase<true, false, I_>(
                g, tid, hhi, hlo, (t != 0),
                (const void*)(input_seq + (size_t)t * B_ * I_), nullptr,
                WhhE_h, WhhE_l, WihE_h, WihE_l, b_ih_enc, b_hh_enc,
                c_enc, ctx_seq + (size_t)t * BH_, elo[(t + 1) & 1], Gt);
            BAR();
        }
    }
    // encoder final h: hi = ctx_seq[T-1], lo = elo0 (T even)

    // ================= P = ctx_seq @ Wc^T + b_attn (fp16 dual region) ======
    {
        for (int i = 0; i < 16; i++) {
            const int it = wg * 16 + i;            // 32768 tile-iters
            const int rowtile = it >> 3;           // 0..4095 (16 rows each)
            const int colbase = (it & 7) << 7;     // 0,128,...,896
            const size_t aoff = ((size_t)rowtile * 16 + l15) * H_;
            f32x4 acch[8], accl[8];
            #pragma unroll
            for (int nt = 0; nt < 8; nt++) {
                acch[nt] = {0.f,0.f,0.f,0.f}; accl[nt] = acch[nt];
            }
            for (int kc = 0; kc < H_; kc += 32) {
                const int ko = kc + quad * 8;
                const bf16x8 ah = ld8(ctx_seq + aoff + ko);
                #pragma unroll
                for (int nt = 0; nt < 8; nt++) {
                    const size_t woff = (size_t)(colbase + (nt << 4) + l15) * H_;
                    const bf16x8 bh = ld8(Wc_h + woff + ko);
                    const bf16x8 bl = ld8(Wc_l + woff + ko);
                    acch[nt] = mfma16(ah, bh, acch[nt]);
                    accl[nt] = mfma16(ah, bl, accl[nt]);
                }
            }
            const size_t orow0 = (size_t)rowtile * 16 + quad * 4;
            #pragma unroll
            for (int nt = 0; nt < 8; nt++) {
                const int col = colbase + (nt << 4) + l15;
                const float bv = b_attn[col];
                #pragma unroll
                for (int r = 0; r < 4; r++) {
                    const float vv = acch[nt][r] + accl[nt][r] + bv;
                    const size_t idx = (orow0 + r) * H_ + col;
                    if (idx < HALF_IDX) P0[idx] = (_Float16)vv;
                    else                P1[idx - HALF_IDX] = (_Float16)vv;
                }
            }
        }
    }
    BAR();

    // ================= decoder: LEN steps ==================================
    float c_dec = 0.f;
    ushort* dhh[2] = {dhh0, dhh1};
    ushort* dhl[2] = {dhl0, dhl1};
    for (int s = 0; s < LEN; s++) {
        const ushort* hi_in = (s == 0) ? ctx_seq + (size_t)(T_ - 1) * BH_ : dhh[s & 1];
        const ushort* lo_in = (s == 0) ? elo0 : dhl[s & 1];

        // ---- (a) q = h @ Wh^T (512 wave-tiles) ----
        if (wg < 512) {
            const int rowbase = (wg >> 6) << 4;
            const int col = ((wg & 63) << 4) + l15;
            const f32x4 res = mm16_split<H_>(hi_in, lo_in,
                (size_t)(rowbase + l15) * H_, Wh_h, Wh_l, (size_t)col * H_, quad);
            #pragma unroll
            for (int r = 0; r < 4; r++)
                qbuf[(size_t)(rowbase + quad * 4 + r) * H_ + col] = res[r];
        }
        BAR();

        // ---- (b) scores[b][t] = sum_h v*tanh(q + P) (65536 wave-units) ----
        for (int i = 0; i < 32; i++) {
            const int u = wg * 32 + i;
            const int t = u >> 7, b = u & 127;
            const size_t base = (size_t)(t * B_ + b) * H_ + (lane << 4);
            const _Float16* pp = (base < HALF_IDX) ? (P0 + base) : (P1 + (base - HALF_IDX));
            const half8 u0 = *(const half8*)(const void*)pp;
            const half8 u1 = *(const half8*)(const void*)(pp + 8);
            const float* qp = qbuf + b * H_ + (lane << 4);
            const float* vp = vvec + (lane << 4);
            float sum = 0.f;
            #pragma unroll
            for (int j0 = 0; j0 < 4; j0++) {
                const float4 qv = *(const float4*)(qp + j0 * 4);
                const float4 vv = *(const float4*)(vp + j0 * 4);
                const int j4 = j0 * 4;
                const float p0 = (j4 < 8) ? (float)u0[j4 & 7]       : (float)u1[j4 & 7];
                const float p1 = (j4+1 < 8) ? (float)u0[(j4+1) & 7] : (float)u1[(j4+1) & 7];
                const float p2 = (j4+2 < 8) ? (float)u0[(j4+2) & 7] : (float)u1[(j4+2) & 7];
                const float p3 = (j4+3 < 8) ? (float)u0[(j4+3) & 7] : (float)u1[(j4+3) & 7];
                sum += vv.x * fast_tanh(qv.x + p0);
                sum += vv.y * fast_tanh(qv.y + p1);
                sum += vv.z * fast_tanh(qv.z + p2);
                sum += vv.w * fast_tanh(qv.w + p3);
            }
            #pragma unroll
            for (int off = 32; off; off >>= 1) sum += __shfl_down(sum, off);
            if (lane == 0) scores[b * T_ + t] = sum;
        }
        BAR();

        // ---- (c) softmax over t, wave per batch row ----
        if (wg < B_) {
            const int b = wg;
            float sv[8];
            float m = -1e30f;
            #pragma unroll
            for (int j = 0; j < 8; j++) {
                sv[j] = scores[b * T_ + (j << 6) + lane];
                m = fmaxf(m, sv[j]);
            }
            #pragma unroll
            for (int off = 32; off; off >>= 1) m = fmaxf(m, __shfl_down(m, off));
            const float mx = __shfl(m, 0);
            float sum = 0.f;
            #pragma unroll
            for (int j = 0; j < 8; j++) { sv[j] = __expf(sv[j] - mx); sum += sv[j]; }
            #pragma unroll
            for (int off = 32; off; off >>= 1) sum += __shfl_down(sum, off);
            const float inv = 1.f / __shfl(sum, 0);
            #pragma unroll
            for (int j = 0; j < 8; j++) scores[b * T_ + (j << 6) + lane] = sv[j] * inv;
        }
        BAR();

        // ---- (d) context = sum_t w[t]*ctx[t], split write ----
        {
            const int flat = g * BS_ + tid;
            if (flat < 65536) {
                const int b = flat >> 9;
                const int h2 = (flat & 511) << 1;
                const float* wb = scores + b * T_;
                const ushort* cp = ctx_seq + ((size_t)b * H_ + h2);
                float a0 = 0.f, a1 = 0.f;
                #pragma unroll 4
                for (int t = 0; t < T_; t++) {
                    const float w = wb[t];
                    const ushort2 uu = *(const ushort2*)(cp + (size_t)t * BH_);
                    a0 += w * bf2f(uu.x);
                    a1 += w * bf2f(uu.y);
                }
                const size_t i0 = (size_t)b * H_ + h2;
                const ushort q0 = f2bf(a0), q1 = f2bf(a1);
                chi[i0] = q0;     clo[i0] = f2bf(a0 - bf2f(q0));
                chi[i0 + 1] = q1; clo[i0 + 1] = f2bf(a1 - bf2f(q1));
            }
        }
        BAR();

        // ---- (e) decoder LSTM cell (weights split on the fly) ----
        lstm_phase<false, true, H_>(
            g, tid, hi_in, lo_in, true,
            (const void*)chi, clo,
            W_hh_dec, nullptr, W_ih_dec, nullptr, b_ih_dec, b_hh_dec,
            c_dec, dhh[(s + 1) & 1], dhl[(s + 1) & 1], Gt);
        BAR();

        // ---- (f) d1 = relu(h @ Wdec^T + b_dec), split write ----
        if (wg < 512) {
            const int rowbase = (wg >> 6) << 4;
            const int col = ((wg & 63) << 4) + l15;
            const f32x4 res = mm16_split<H_>(dhh[(s + 1) & 1], dhl[(s + 1) & 1],
                (size_t)(rowbase + l15) * H_, Wdec_h, Wdec_l, (size_t)col * H_, quad);
            const float bv = b_dec[col];
            #pragma unroll
            for (int r = 0; r < 4; r++) {
                const float vv = fmaxf(res[r] + bv, 0.f);
                const size_t idx = (size_t)(rowbase + quad * 4 + r) * H_ + col;
                const ushort h = f2bf(vv);
                d1h[idx] = h;
                d1l[idx] = f2bf(vv - bf2f(h));
            }
        }
        BAR();

        // ---- (g) out = d1 @ Wout^T + b_out (128 wave-tiles) ----
        if (wg < 128) {
            const int rowbase = (wg >> 4) << 4;
            const int col = ((wg & 15) << 4) + l15;
            const f32x4 res = mm16_split<H_>(d1h, d1l,
                (size_t)(rowbase + l15) * H_, Wout_h, Wout_l, (size_t)col * H_, quad);
            const float bv = b_out[col];
            float* op = out + (size_t)s * B_ * O_;
            #pragma unroll
            for (int r = 0; r < 4; r++)
                op[(size_t)(rowbase + quad * 4 + r) * O_ + col] = res[r] + bv;
        }
        BAR();
    }
}

// ---------------------------------------------------------------------------
extern "C" void kernel_launch(void* const* d_in, const int* in_sizes, int n_in,
                              void* d_out, int out_size, void* d_ws, size_t ws_size,
                              hipStream_t stream)
{
    const float* input_seq = (const float*)d_in[0];
    const float* W_ih_enc  = (const float*)d_in[1];
    const float* W_hh_enc  = (const float*)d_in[2];
    const float* b_ih_enc  = (const float*)d_in[3];
    const float* b_hh_enc  = (const float*)d_in[4];
    const float* W_attn    = (const float*)d_in[5];
    const float* b_attn    = (const float*)d_in[6];
    const float* v         = (const float*)d_in[7];
    const float* W_ih_dec  = (const float*)d_in[8];
    const float* W_hh_dec  = (const float*)d_in[9];
    const float* b_ih_dec  = (const float*)d_in[10];
    const float* b_hh_dec  = (const float*)d_in[11];
    const float* W_dec     = (const float*)d_in[12];
    const float* b_dec     = (const float*)d_in[13];
    const float* W_out     = (const float*)d_in[14];
    const float* b_out     = (const float*)d_in[15];
    float* out = (float*)d_out;
    const int LEN = out_size / (B_ * O_);   // 30
    const int layoutA = (ws_size >= WS_NEED_A) ? 1 : 0;

    hipMemsetAsync(d_ws, 0, 256, stream);   // barrier counter
    mega_kernel<<<NB_, BS_, 0, stream>>>(
        input_seq, W_ih_enc, W_hh_enc, b_ih_enc, b_hh_enc,
        W_attn, b_attn, v, W_ih_dec, W_hh_dec, b_ih_dec, b_hh_dec,
        W_dec, b_dec, W_out, b_out, out, (char*)d_ws, LEN, layoutA);
    (void)in_sizes; (void)n_in;
}